// Round 1
// baseline (73.168 us; speedup 1.0000x reference)
//
#include <hip/hip_runtime.h>

#define N_NODES 512
#define DIM 128
#define MAX_PATH 5
#define NUM_EDGES 8192

// Kernel 1: T[e][p] = dot(edge_embedding[e, :], edge_vector[p, :])
// One wave (64 lanes) per edge; each lane holds 2 consecutive floats (float2).
__global__ void edge_dot_table_kernel(const float* __restrict__ edge_embedding,
                                      const float* __restrict__ edge_vector,
                                      float* __restrict__ table) {
    const int lane = threadIdx.x & 63;
    const int wave_in_block = threadIdx.x >> 6;
    const int e = blockIdx.x * (blockDim.x >> 6) + wave_in_block;
    if (e >= NUM_EDGES) return;

    const float2 eb = *reinterpret_cast<const float2*>(
        &edge_embedding[e * DIM + lane * 2]);

#pragma unroll
    for (int p = 0; p < MAX_PATH; ++p) {
        const float2 ev = *reinterpret_cast<const float2*>(
            &edge_vector[p * DIM + lane * 2]);
        float partial = eb.x * ev.x + eb.y * ev.y;
#pragma unroll
        for (int off = 32; off >= 1; off >>= 1)
            partial += __shfl_xor(partial, off, 64);
        if (lane == 0) table[e * MAX_PATH + p] = partial;
    }
}

// Kernel 2: per (i,j) pair, gather up to MAX_PATH table entries, masked sum,
// divide by path length (0-length paths output 0 since sum==0).
__global__ void edge_enc_kernel(const int* __restrict__ edge_paths,
                                const float* __restrict__ table,
                                float* __restrict__ out) {
    const int pair = blockIdx.x * blockDim.x + threadIdx.x;
    if (pair >= N_NODES * N_NODES) return;

    const int* __restrict__ paths = &edge_paths[pair * MAX_PATH];
    float sum = 0.0f;
    int len = 0;
#pragma unroll
    for (int p = 0; p < MAX_PATH; ++p) {
        const int e = paths[p];
        if (e >= 0) {
            sum += table[e * MAX_PATH + p];
            ++len;
        }
    }
    out[pair] = sum / (float)(len > 0 ? len : 1);
}

extern "C" void kernel_launch(void* const* d_in, const int* in_sizes, int n_in,
                              void* d_out, int out_size, void* d_ws, size_t ws_size,
                              hipStream_t stream) {
    // d_in[0] = x (unused by reference)
    const float* edge_embedding = (const float*)d_in[1];   // (E, DIM) f32
    const int*   edge_paths     = (const int*)d_in[2];     // (N, N, P) i32
    const float* edge_vector    = (const float*)d_in[3];   // (P, DIM) f32
    float* out = (float*)d_out;                            // (N, N) f32

    float* table = (float*)d_ws;                           // E * MAX_PATH floats = 160 KB

    // Kernel 1: 8192 edges, 4 waves (256 threads) per block -> 2048 blocks.
    const int waves_per_block = 4;
    const int blocks1 = NUM_EDGES / waves_per_block;
    edge_dot_table_kernel<<<blocks1, waves_per_block * 64, 0, stream>>>(
        edge_embedding, edge_vector, table);

    // Kernel 2: one thread per (i,j) pair.
    const int pairs = N_NODES * N_NODES;
    const int blocks2 = (pairs + 255) / 256;
    edge_enc_kernel<<<blocks2, 256, 0, stream>>>(edge_paths, table, out);
}